// Round 8
// baseline (231.192 us; speedup 1.0000x reference)
//
#include <hip/hip_runtime.h>
#include <hip/hip_bf16.h>
#include <math.h>

#define TOKS 49152   // B*T
#define HD   512     // hidden
#define GN   2       // groups
#define CN   320     // codes per group
#define DN   128     // code dim
#define BM   64      // tokens per block (main path)
#define NTHR 512     // 8 waves: 2 row-groups x 4 col-groups
#define LSTR 324     // lg row stride (324%32==4 -> 2-way lg writes, free)

// per-buffer LDS layout (bytes)
#define BH_OFF 0
#define BL_OFF 20480
#define AH_OFF 40960
#define AL_OFF 45056
#define SBUF   49152
#define SMEM_DYN (2 * SBUF)          // 96 KiB dynamic LDS
#define PSUM_OFF 41472               // epilogue psum (lg = 32*324*4 = 41472)

#define BMF  32      // fp32 fallback geometry (round-3 verified)
#define NTHRF 256
#define WSTR 33

#define WS_WELEMS ((size_t)(GN * CN) * HD)   // 327680
#define WS_W_OFF  4096
#define WS_MID    (WS_W_OFF + 4 * WS_WELEMS) // pp + wh + wl (~1.3 MB)

typedef _Float16 f16x8 __attribute__((ext_vector_type(8)));
typedef float    fx4   __attribute__((ext_vector_type(4)));

#define GLD_LDS16(gp, lp)                                                    \
  __builtin_amdgcn_global_load_lds(                                          \
      (const __attribute__((address_space(1))) void*)(gp),                   \
      (__attribute__((address_space(3))) void*)(lp), 16, 0, 0)

// ---------------- zero the p-accumulator (fallback path) ----------------
__global__ void k_zero(float* pp) {
  int t = threadIdx.x;
  if (t < GN * CN) pp[t] = 0.f;
}

// -------- W fragment-major (hi, lo*512) f16 splitter + pp zero ----------
__global__ __launch_bounds__(256) void k_split(const float* __restrict__ src,
                                               _Float16* __restrict__ dh,
                                               _Float16* __restrict__ dl,
                                               float* __restrict__ pp) {
  if (blockIdx.x < 3) {
    int i = blockIdx.x * 256 + threadIdx.x;
    if (i < GN * CN) pp[i] = 0.f;
  }
  size_t t    = (size_t)blockIdx.x * 256 + threadIdx.x;
  int    lane = (int)(t & 63);
  size_t blob = t >> 6;
  int    k0   = (int)(blob & 15);
  size_t rb   = blob >> 4;
  const float* p = src + (rb * 16 + (lane & 15)) * HD + k0 * 32 + (lane >> 4) * 8;
  fx4 u = *(const fx4*)p;
  fx4 v = *(const fx4*)(p + 4);
  f16x8 h8, l8;
  #pragma unroll
  for (int e = 0; e < 4; ++e) {
    _Float16 hu = (_Float16)u[e], hv = (_Float16)v[e];
    h8[e]     = hu;
    h8[e + 4] = hv;
    l8[e]     = (_Float16)((u[e] - (float)hu) * 512.f);
    l8[e + 4] = (_Float16)((v[e] - (float)hv) * 512.f);
  }
  *(f16x8*)(dh + t * 8) = h8;
  *(f16x8*)(dl + t * 8) = l8;
}

// ---------------- fused MFMA GEMM + epilogue (double-buffered LDS) -------
// grid 1536; u -> mt=((u>>4)<<3)|(u&7), g=(u>>3)&1: g-twins of an m-tile on
// the SAME XCD -> x L2 reuse. Per K-step: STAGE(t+1 -> buf^1) issued BEFORE
// COMPUTE(buf); ONE barrier per step (T3 minimum 2-phase). A is converted to
// frag-major f16 h/l during staging by 256 threads -> zero CVT in k-loop.
__global__ __launch_bounds__(NTHR, 2) void k_gemm_ep(
    const float* __restrict__ x, const int* __restrict__ mask,
    const float* __restrict__ gnoise, const float* __restrict__ bias,
    const float* __restrict__ cv, const _Float16* __restrict__ wh,
    const _Float16* __restrict__ wl, float* __restrict__ out,
    float* __restrict__ pp)
{
  extern __shared__ __align__(16) char smem[];   // 96 KiB dynamic
  float* lg   = (float*)smem;                    // epilogue [32][LSTR]
  float* psum = (float*)(smem + PSUM_OFF);       // epilogue [8][CN]

  const int u   = blockIdx.x;
  const int mt  = ((u >> 4) << 3) | (u & 7);
  const int g   = (u >> 3) & 1;
  const int m0  = mt * BM;
  const int tid = threadIdx.x;
  const int tc  = tid & 63;
  const int w   = tid >> 6;          // wave 0..7
  const int wr  = w >> 2;            // row-group 0..1 (32 rows)
  const int wc  = w & 3;             // col-group 0..3 (80 cols)
  const int l15 = tid & 15;
  const int l4  = tc >> 4;

  fx4 aH[2][5], aL[2][5];
  #pragma unroll
  for (int rf = 0; rf < 2; ++rf)
    #pragma unroll
    for (int cf = 0; cf < 5; ++cf) {
      aH[rf][cf] = (fx4){0.f, 0.f, 0.f, 0.f};
      aL[rf][cf] = (fx4){0.f, 0.f, 0.f, 0.f};
    }

  // B staging: wave w stages blobs w*5..w*5+4 (w<4: hi, w>=4: lo)
  const _Float16* bb = (w < 4) ? wh : wl;
  const int cb0      = (w < 4) ? w * 5 : w * 5 - 20;
  const _Float16* bsrc = bb + (size_t)(g * 20 + cb0) * 8192 + (size_t)tc * 8;
  // A staging (threads 0..255): row = tid>>2, k-chunk = tid&3 (8 f32)
  const int arow = tid >> 2;
  const int al4  = tid & 3;
  const float* asrc = x + (size_t)(m0 + arow) * HD + al4 * 8;
  const int aslot = (arow >> 4) * 1024 + ((arow & 15) + 16 * al4) * 16;

#define STAGE(T, BASE) do {                                                  \
    _Pragma("unroll")                                                        \
    for (int q = 0; q < 5; ++q)                                              \
      GLD_LDS16(bsrc + (size_t)q * 8192 + (size_t)(T) * 512,                 \
                (BASE) + w * 5120 + q * 1024);                               \
    if (tid < 256) {                                                         \
      fx4 au = *(const fx4*)(asrc + (size_t)(T) * 32);                       \
      fx4 av = *(const fx4*)(asrc + (size_t)(T) * 32 + 4);                   \
      f16x8 h8, l8;                                                          \
      _Pragma("unroll")                                                      \
      for (int e = 0; e < 4; ++e) {                                          \
        _Float16 hh;                                                         \
        hh = (_Float16)au[e]; h8[e] = hh;                                    \
        l8[e] = (_Float16)((au[e] - (float)hh) * 512.f);                     \
        hh = (_Float16)av[e]; h8[e + 4] = hh;                                \
        l8[e + 4] = (_Float16)((av[e] - (float)hh) * 512.f);                 \
      }                                                                      \
      *(f16x8*)((BASE) + AH_OFF + aslot) = h8;                               \
      *(f16x8*)((BASE) + AL_OFF + aslot) = l8;                               \
    }                                                                        \
  } while (0)

#define COMPUTE(BASE) do {                                                   \
    f16x8 A0h = *(const f16x8*)((BASE) + AH_OFF + (wr * 2 + 0) * 1024 + tc * 16); \
    f16x8 A1h = *(const f16x8*)((BASE) + AH_OFF + (wr * 2 + 1) * 1024 + tc * 16); \
    f16x8 A0l = *(const f16x8*)((BASE) + AL_OFF + (wr * 2 + 0) * 1024 + tc * 16); \
    f16x8 A1l = *(const f16x8*)((BASE) + AL_OFF + (wr * 2 + 1) * 1024 + tc * 16); \
    _Pragma("unroll")                                                        \
    for (int cf = 0; cf < 5; ++cf) {                                         \
      f16x8 Bh = *(const f16x8*)((BASE) + BH_OFF + (wc * 5 + cf) * 1024 + tc * 16); \
      f16x8 Bl = *(const f16x8*)((BASE) + BL_OFF + (wc * 5 + cf) * 1024 + tc * 16); \
      aH[0][cf] = __builtin_amdgcn_mfma_f32_16x16x32_f16(A0h, Bh, aH[0][cf], 0, 0, 0); \
      aH[1][cf] = __builtin_amdgcn_mfma_f32_16x16x32_f16(A1h, Bh, aH[1][cf], 0, 0, 0); \
      aL[0][cf] = __builtin_amdgcn_mfma_f32_16x16x32_f16(A0h, Bl, aL[0][cf], 0, 0, 0); \
      aL[0][cf] = __builtin_amdgcn_mfma_f32_16x16x32_f16(A0l, Bh, aL[0][cf], 0, 0, 0); \
      aL[1][cf] = __builtin_amdgcn_mfma_f32_16x16x32_f16(A1h, Bl, aL[1][cf], 0, 0, 0); \
      aL[1][cf] = __builtin_amdgcn_mfma_f32_16x16x32_f16(A1l, Bh, aL[1][cf], 0, 0, 0); \
    }                                                                        \
  } while (0)

  STAGE(0, smem);
  __syncthreads();                       // buf0 staged (drains DMA)
  #pragma unroll 2
  for (int t = 0; t < 16; ++t) {
    char* cur = smem + (size_t)(t & 1) * SBUF;
    char* nxt = smem + (size_t)((t & 1) ^ 1) * SBUF;
    if (t < 15) STAGE(t + 1, nxt);       // async DMA flies under COMPUTE
    COMPUTE(cur);
    __syncthreads();                     // one barrier per K-step
  }
#undef STAGE
#undef COMPUTE

  float bj[5];
  #pragma unroll
  for (int cf = 0; cf < 5; ++cf) bj[cf] = bias[g * CN + wc * 80 + cf * 16 + l15];

  // two 32-row epilogue phases (lg aliases buf0; staged data dead)
  float pacc[5] = {0.f, 0.f, 0.f, 0.f, 0.f};
  #pragma unroll
  for (int p = 0; p < 2; ++p) {
    if (wr == p) {
      // C/D layout (HW-verified r4-r7): col = l15, row = l4*4 + e
      #pragma unroll
      for (int cf = 0; cf < 5; ++cf) {
        const int col = wc * 80 + cf * 16 + l15;
        #pragma unroll
        for (int rf = 0; rf < 2; ++rf)
          #pragma unroll
          for (int e = 0; e < 4; ++e)
            lg[(rf * 16 + l4 * 4 + e) * LSTR + col] =
                aH[rf][cf][e] + aL[rf][cf][e] * (1.f / 512.f) + bj[cf];
      }
    }
    __syncthreads();
    // all 8 waves: 4 rows each (verified row epilogue, r3-r7)
    #pragma unroll
    for (int i = 0; i < 4; ++i) {
      const int rl = w * 4 + i;
      const int n  = m0 + p * 32 + rl;
      const size_t grow = ((size_t)n * GN + g) * CN;
      float lv[5], gv[5];
      #pragma unroll
      for (int j = 0; j < 5; ++j) lv[j] = lg[rl * LSTR + tc + 64 * j];
      #pragma unroll
      for (int j = 0; j < 5; ++j) gv[j] = gnoise[grow + tc + 64 * j];

      float bv = -3.4e38f; int bi = 1 << 30;
      #pragma unroll
      for (int j = 0; j < 5; ++j) {
        float v = lv[j] + gv[j];
        if (v > bv) { bv = v; bi = tc + 64 * j; }
      }
      for (int off = 1; off < 64; off <<= 1) {
        float ov = __shfl_xor(bv, off);
        int   oi = __shfl_xor(bi, off);
        if (ov > bv || (ov == bv && oi < bi)) { bv = ov; bi = oi; }
      }

      float mx = lv[0];
      #pragma unroll
      for (int j = 1; j < 5; ++j) mx = fmaxf(mx, lv[j]);
      for (int off = 1; off < 64; off <<= 1) mx = fmaxf(mx, __shfl_xor(mx, off));
      float e[5], s = 0.f;
      #pragma unroll
      for (int j = 0; j < 5; ++j) { e[j] = __expf(lv[j] - mx); s += e[j]; }
      for (int off = 1; off < 64; off <<= 1) s += __shfl_xor(s, off);
      const float inv = 1.f / s;
      const float mlt = (mask[n] != 0) ? 1.f : 0.f;
      #pragma unroll
      for (int j = 0; j < 5; ++j) pacc[j] += mlt * e[j] * inv;

      const float2* cvr = (const float2*)(cv + ((size_t)(g * CN + bi)) * DN);
      float2* o2 = (float2*)(out + (size_t)n * (GN * DN) + g * DN);
      o2[tc] = cvr[tc];
    }
    __syncthreads();
  }

  #pragma unroll
  for (int j = 0; j < 5; ++j) psum[w * CN + tc + 64 * j] = pacc[j];
  __syncthreads();
  for (int c = tid; c < CN; c += NTHR) {
    float s = 0.f;
    #pragma unroll
    for (int q = 0; q < 8; ++q) s += psum[q * CN + c];
    atomicAdd(&pp[g * CN + c], s);
  }
}

// ---------------- fp32 fallback (round-3 verified, BMF=32) ----------------
__global__ __launch_bounds__(NTHRF) void k_main_fp32(
    const float* __restrict__ x, const int* __restrict__ mask,
    const float* __restrict__ gnoise, const float* __restrict__ W,
    const float* __restrict__ bias, const float* __restrict__ cv,
    float* __restrict__ out, float* __restrict__ pp)
{
  __shared__ __align__(16) char fsmem[47360];
  float* w_lds = (float*)fsmem;
  float* xs    = (float*)(fsmem + 42240);
  float* lgf   = (float*)fsmem;
  float* psum  = (float*)(fsmem + 42240);

  const int m0  = blockIdx.x * BMF;
  const int g   = blockIdx.y;
  const int tid = threadIdx.x;
  const int tc  = tid & 63;
  const int tr  = tid >> 6;
  const int r0  = tr * 8;

  float acc[8][5];
  #pragma unroll
  for (int i = 0; i < 8; ++i)
    #pragma unroll
    for (int j = 0; j < 5; ++j) acc[i][j] = 0.f;

  const float* Wg = W + (size_t)g * CN * HD;

  for (int k0 = 0; k0 < HD; k0 += 32) {
    __syncthreads();
    #pragma unroll
    for (int t = 0; t < 10; ++t) {
      int idx = tid + t * NTHRF;
      int c   = idx >> 3;
      int k4  = idx & 7;
      float4 wv4 = *(const float4*)(Wg + (size_t)c * HD + k0 + k4 * 4);
      float* dst = &w_lds[c * WSTR + k4 * 4];
      dst[0] = wv4.x; dst[1] = wv4.y; dst[2] = wv4.z; dst[3] = wv4.w;
    }
    {
      int r = tid >> 3, k4 = tid & 7;
      float4 xv = *(const float4*)(x + (size_t)(m0 + r) * HD + k0 + k4 * 4);
      float* dst = &xs[r * 32 + k4 * 4];
      dst[0] = xv.x; dst[1] = xv.y; dst[2] = xv.z; dst[3] = xv.w;
    }
    __syncthreads();
    #pragma unroll
    for (int kk = 0; kk < 32; kk += 4) {
      float xq[8][4];
      #pragma unroll
      for (int i = 0; i < 8; ++i) {
        float4 t4 = *(const float4*)&xs[(r0 + i) * 32 + kk];
        xq[i][0] = t4.x; xq[i][1] = t4.y; xq[i][2] = t4.z; xq[i][3] = t4.w;
      }
      #pragma unroll
      for (int q = 0; q < 4; ++q) {
        float wv[5];
        #pragma unroll
        for (int j = 0; j < 5; ++j) wv[j] = w_lds[(tc + 64 * j) * WSTR + kk + q];
        #pragma unroll
        for (int i = 0; i < 8; ++i)
          #pragma unroll
          for (int j = 0; j < 5; ++j)
            acc[i][j] = fmaf(xq[i][q], wv[j], acc[i][j]);
      }
    }
  }
  __syncthreads();

  float bj[5];
  #pragma unroll
  for (int j = 0; j < 5; ++j) bj[j] = bias[g * CN + tc + 64 * j];
  #pragma unroll
  for (int i = 0; i < 8; ++i)
    #pragma unroll
    for (int j = 0; j < 5; ++j)
      lgf[(r0 + i) * CN + tc + 64 * j] = acc[i][j] + bj[j];
  __syncthreads();

  float pacc[5] = {0.f, 0.f, 0.f, 0.f, 0.f};
  #pragma unroll
  for (int i = 0; i < 8; ++i) {
    const int r = r0 + i;
    const int n = m0 + r;
    const size_t grow = ((size_t)n * GN + g) * CN;
    float lv[5], gv[5];
    #pragma unroll
    for (int j = 0; j < 5; ++j) lv[j] = lgf[r * CN + tc + 64 * j];
    #pragma unroll
    for (int j = 0; j < 5; ++j) gv[j] = gnoise[grow + tc + 64 * j];

    float bv = -3.4e38f; int bi = 1 << 30;
    #pragma unroll
    for (int j = 0; j < 5; ++j) {
      float v = lv[j] + gv[j];
      if (v > bv) { bv = v; bi = tc + 64 * j; }
    }
    for (int off = 1; off < 64; off <<= 1) {
      float ov = __shfl_xor(bv, off);
      int   oi = __shfl_xor(bi, off);
      if (ov > bv || (ov == bv && oi < bi)) { bv = ov; bi = oi; }
    }

    float mx = lv[0];
    #pragma unroll
    for (int j = 1; j < 5; ++j) mx = fmaxf(mx, lv[j]);
    for (int off = 1; off < 64; off <<= 1) mx = fmaxf(mx, __shfl_xor(mx, off));
    float e[5], s = 0.f;
    #pragma unroll
    for (int j = 0; j < 5; ++j) { e[j] = expf(lv[j] - mx); s += e[j]; }
    for (int off = 1; off < 64; off <<= 1) s += __shfl_xor(s, off);
    const float inv = 1.f / s;
    const float mlt = (mask[n] != 0) ? 1.f : 0.f;
    #pragma unroll
    for (int j = 0; j < 5; ++j) pacc[j] += mlt * e[j] * inv;

    const float2* cvr = (const float2*)(cv + ((size_t)(g * CN + bi)) * DN);
    float2* o2 = (float2*)(out + (size_t)n * (GN * DN) + g * DN);
    o2[tc] = cvr[tc];
  }

  #pragma unroll
  for (int j = 0; j < 5; ++j) psum[tr * CN + tc + 64 * j] = pacc[j];
  __syncthreads();
  for (int c = tid; c < CN; c += NTHRF) {
    float s = psum[c] + psum[CN + c] + psum[2 * CN + c] + psum[3 * CN + c];
    atomicAdd(&pp[g * CN + c], s);
  }
}

// ---------------- perplexity finalize ----------------
__global__ __launch_bounds__(640) void k_final(
    const float* __restrict__ pp, const int* __restrict__ mask,
    float* __restrict__ out, int out_off)
{
  __shared__ float red[10];
  __shared__ float eL[GN * CN];
  __shared__ float perp_parts[GN];
  const int tid = threadIdx.x;

  float cnt = 0.f;
  for (int i = tid; i < TOKS; i += 640) cnt += (mask[i] != 0) ? 1.f : 0.f;
  for (int off = 1; off < 64; off <<= 1) cnt += __shfl_xor(cnt, off);
  if ((tid & 63) == 0) red[tid >> 6] = cnt;
  __syncthreads();
  float denom = 0.f;
  #pragma unroll
  for (int w = 0; w < 10; ++w) denom += red[w];
  denom = fmaxf(denom, 1.f);

  const float p = pp[tid] / denom;
  eL[tid] = p * logf(p + 1e-7f);
  __syncthreads();

  if (tid < 2 * 64) {
    const int gg = tid >> 6, ll = tid & 63;
    float s = 0.f;
    #pragma unroll
    for (int j = 0; j < 5; ++j) s += eL[gg * CN + ll + 64 * j];
    for (int off = 1; off < 64; off <<= 1) s += __shfl_xor(s, off);
    if (ll == 0) perp_parts[gg] = expf(-s);
  }
  __syncthreads();
  if (tid == 0) out[out_off] = perp_parts[0] + perp_parts[1];
}

extern "C" void kernel_launch(void* const* d_in, const int* in_sizes, int n_in,
                              void* d_out, int out_size, void* d_ws, size_t ws_size,
                              hipStream_t stream) {
  const float* x     = (const float*)d_in[0];
  const int*   mask  = (const int*)d_in[1];
  const float* gn    = (const float*)d_in[2];
  const float* W     = (const float*)d_in[3];
  const float* bias  = (const float*)d_in[4];
  const float* cv    = (const float*)d_in[5];
  float* out = (float*)d_out;
  float* pp  = (float*)d_ws;

  if (ws_size >= WS_MID) {
    _Float16* wh = (_Float16*)((char*)d_ws + WS_W_OFF);
    _Float16* wl = wh + WS_WELEMS;
    hipLaunchKernelGGL(k_split, dim3((int)(WS_WELEMS / 8 / 256)), dim3(256), 0,
                       stream, W, wh, wl, pp);
    hipLaunchKernelGGL(k_gemm_ep, dim3(TOKS / BM * GN), dim3(NTHR), SMEM_DYN,
                       stream, x, mask, gn, bias, cv, wh, wl, out, pp);
  } else {
    hipLaunchKernelGGL(k_zero, dim3(1), dim3(640), 0, stream, pp);
    hipLaunchKernelGGL(k_main_fp32, dim3(TOKS / BMF, GN), dim3(NTHRF), 0, stream,
                       x, mask, gn, W, bias, cv, out, pp);
  }

  hipLaunchKernelGGL(k_final, dim3(1), dim3(640), 0, stream,
                     pp, mask, out, out_size - 1);
}

// Round 9
// 207.799 us; speedup vs baseline: 1.1126x; 1.1126x over previous
//
#include <hip/hip_runtime.h>
#include <hip/hip_bf16.h>
#include <math.h>

#define TOKS 49152   // B*T
#define HD   512     // hidden
#define GN   2       // groups
#define CN   320     // codes per group
#define DN   128     // code dim
#define BM   128     // tokens per block (main path)
#define NTHR 512     // 8 waves: 2 row-groups(64) x 4 col-groups(80)
#define LSTR 324     // lg row stride (324%32==4 -> 2-way lg writes, free)

// per-buffer LDS layout (bytes): Bh 20K | Bl 20K | Ah 8K | Al 8K
#define BH_OFF 0
#define BL_OFF 20480
#define AH_OFF 40960
#define AL_OFF 49152
#define SBUF   57344
#define SMEM_DYN (2 * SBUF)          // 112 KiB dynamic LDS (96K proven r8)
#define PSUM_OFF 82944               // after lg = 64*324*4 B

#define BMF  32      // fp32 fallback geometry (round-3 verified)
#define NTHRF 256
#define WSTR 33

#define WS_WELEMS ((size_t)(GN * CN) * HD)   // 327680
#define WS_W_OFF  4096
#define WS_MID    (WS_W_OFF + 4 * WS_WELEMS) // pp + wh + wl (~1.3 MB)

typedef _Float16 f16x8 __attribute__((ext_vector_type(8)));
typedef float    fx4   __attribute__((ext_vector_type(4)));

#define GLD_LDS16(gp, lp)                                                    \
  __builtin_amdgcn_global_load_lds(                                          \
      (const __attribute__((address_space(1))) void*)(gp),                   \
      (__attribute__((address_space(3))) void*)(lp), 16, 0, 0)

// ---------------- zero the p-accumulator (fallback path) ----------------
__global__ void k_zero(float* pp) {
  int t = threadIdx.x;
  if (t < GN * CN) pp[t] = 0.f;
}

// -------- W fragment-major (hi, lo*512) f16 splitter + pp zero ----------
__global__ __launch_bounds__(256) void k_split(const float* __restrict__ src,
                                               _Float16* __restrict__ dh,
                                               _Float16* __restrict__ dl,
                                               float* __restrict__ pp) {
  if (blockIdx.x < 3) {
    int i = blockIdx.x * 256 + threadIdx.x;
    if (i < GN * CN) pp[i] = 0.f;
  }
  size_t t    = (size_t)blockIdx.x * 256 + threadIdx.x;
  int    lane = (int)(t & 63);
  size_t blob = t >> 6;
  int    k0   = (int)(blob & 15);
  size_t rb   = blob >> 4;
  const float* p = src + (rb * 16 + (lane & 15)) * HD + k0 * 32 + (lane >> 4) * 8;
  fx4 u = *(const fx4*)p;
  fx4 v = *(const fx4*)(p + 4);
  f16x8 h8, l8;
  #pragma unroll
  for (int e = 0; e < 4; ++e) {
    _Float16 hu = (_Float16)u[e], hv = (_Float16)v[e];
    h8[e]     = hu;
    h8[e + 4] = hv;
    l8[e]     = (_Float16)((u[e] - (float)hu) * 512.f);
    l8[e + 4] = (_Float16)((v[e] - (float)hv) * 512.f);
  }
  *(f16x8*)(dh + t * 8) = h8;
  *(f16x8*)(dl + t * 8) = l8;
}

// ---------------- fused MFMA GEMM + epilogue (BM=128, dbuf LDS) ----------
// grid 768; u -> mt=((u>>4)<<3)|(u&7), g=(u>>3)&1: g-twins of an m-tile on
// the SAME XCD -> x L2 reuse. Per K-step: issue A-loads(t+1) + B-DMA(t+1)
// BEFORE COMPUTE(t) (T14 issue-early/write-late); A cvt+ds_write after.
// Per-CU step arithmetic: MFMA 2330 cyc > DMA 730 + LDS 576 -> MFMA-bound.
__global__ __launch_bounds__(NTHR, 2) void k_gemm_ep(
    const float* __restrict__ x, const int* __restrict__ mask,
    const float* __restrict__ gnoise, const float* __restrict__ bias,
    const float* __restrict__ cv, const _Float16* __restrict__ wh,
    const _Float16* __restrict__ wl, float* __restrict__ out,
    float* __restrict__ pp)
{
  extern __shared__ __align__(16) char smem[];   // 112 KiB dynamic
  float* lg   = (float*)smem;                    // epilogue [64][LSTR]
  float* psum = (float*)(smem + PSUM_OFF);       // epilogue [8][CN]

  const int u   = blockIdx.x;
  const int mt  = ((u >> 4) << 3) | (u & 7);
  const int g   = (u >> 3) & 1;
  const int m0  = mt * BM;
  const int tid = threadIdx.x;
  const int tc  = tid & 63;
  const int w   = tid >> 6;          // wave 0..7
  const int wr  = w >> 2;            // row-group 0..1 (64 rows)
  const int wc  = w & 3;             // col-group 0..3 (80 cols)
  const int l15 = tid & 15;
  const int l4  = tc >> 4;

  fx4 aH[4][5], aL[4][5];
  #pragma unroll
  for (int rf = 0; rf < 4; ++rf)
    #pragma unroll
    for (int cf = 0; cf < 5; ++cf) {
      aH[rf][cf] = (fx4){0.f, 0.f, 0.f, 0.f};
      aL[rf][cf] = (fx4){0.f, 0.f, 0.f, 0.f};
    }

  // B staging: wave w stages 5 blobs (w<4: hi, w>=4: lo); dest w*5120+q*1024
  const _Float16* bb = (w < 4) ? wh : wl;
  const int cb0      = (w < 4) ? w * 5 : w * 5 - 20;
  const _Float16* bsrc = bb + (size_t)(g * 20 + cb0) * 8192 + (size_t)tc * 8;
  // A staging: thread = (blob w, slot tc); slot holds row w*16+(tc&15),
  // k-chunk (tc>>4)*8. ds_write/ds_read both slot-linear -> conflict-free.
  const float* asrc = x + (size_t)(m0 + w * 16 + (tc & 15)) * HD + (tc >> 4) * 8;
  const int aslot = w * 1024 + tc * 16;

  fx4 au, av;   // in-flight A loads (issue-early / write-late)

#define STAGE_A_LOAD(T) do {                                                 \
    au = *(const fx4*)(asrc + (size_t)(T) * 32);                             \
    av = *(const fx4*)(asrc + (size_t)(T) * 32 + 4);                         \
  } while (0)

#define STAGE_B(T, BASE) do {                                                \
    _Pragma("unroll")                                                        \
    for (int q = 0; q < 5; ++q)                                              \
      GLD_LDS16(bsrc + (size_t)q * 8192 + (size_t)(T) * 512,                 \
                (BASE) + w * 5120 + q * 1024);                               \
  } while (0)

#define STAGE_A_WRITE(BASE) do {                                             \
    f16x8 h8, l8;                                                            \
    _Pragma("unroll")                                                        \
    for (int e = 0; e < 4; ++e) {                                            \
      _Float16 hh;                                                           \
      hh = (_Float16)au[e]; h8[e] = hh;                                      \
      l8[e] = (_Float16)((au[e] - (float)hh) * 512.f);                       \
      hh = (_Float16)av[e]; h8[e + 4] = hh;                                  \
      l8[e + 4] = (_Float16)((av[e] - (float)hh) * 512.f);                   \
    }                                                                        \
    *(f16x8*)((BASE) + AH_OFF + aslot) = h8;                                 \
    *(f16x8*)((BASE) + AL_OFF + aslot) = l8;                                 \
  } while (0)

#define COMPUTE(BASE) do {                                                   \
    f16x8 Ah0 = *(const f16x8*)((BASE) + AH_OFF + (wr * 4 + 0) * 1024 + tc * 16); \
    f16x8 Ah1 = *(const f16x8*)((BASE) + AH_OFF + (wr * 4 + 1) * 1024 + tc * 16); \
    f16x8 Ah2 = *(const f16x8*)((BASE) + AH_OFF + (wr * 4 + 2) * 1024 + tc * 16); \
    f16x8 Ah3 = *(const f16x8*)((BASE) + AH_OFF + (wr * 4 + 3) * 1024 + tc * 16); \
    f16x8 Al0 = *(const f16x8*)((BASE) + AL_OFF + (wr * 4 + 0) * 1024 + tc * 16); \
    f16x8 Al1 = *(const f16x8*)((BASE) + AL_OFF + (wr * 4 + 1) * 1024 + tc * 16); \
    f16x8 Al2 = *(const f16x8*)((BASE) + AL_OFF + (wr * 4 + 2) * 1024 + tc * 16); \
    f16x8 Al3 = *(const f16x8*)((BASE) + AL_OFF + (wr * 4 + 3) * 1024 + tc * 16); \
    _Pragma("unroll")                                                        \
    for (int cf = 0; cf < 5; ++cf) {                                         \
      f16x8 Bh = *(const f16x8*)((BASE) + BH_OFF + (wc * 5 + cf) * 1024 + tc * 16); \
      f16x8 Bl = *(const f16x8*)((BASE) + BL_OFF + (wc * 5 + cf) * 1024 + tc * 16); \
      aH[0][cf] = __builtin_amdgcn_mfma_f32_16x16x32_f16(Ah0, Bh, aH[0][cf], 0, 0, 0); \
      aH[1][cf] = __builtin_amdgcn_mfma_f32_16x16x32_f16(Ah1, Bh, aH[1][cf], 0, 0, 0); \
      aH[2][cf] = __builtin_amdgcn_mfma_f32_16x16x32_f16(Ah2, Bh, aH[2][cf], 0, 0, 0); \
      aH[3][cf] = __builtin_amdgcn_mfma_f32_16x16x32_f16(Ah3, Bh, aH[3][cf], 0, 0, 0); \
      aL[0][cf] = __builtin_amdgcn_mfma_f32_16x16x32_f16(Ah0, Bl, aL[0][cf], 0, 0, 0); \
      aL[0][cf] = __builtin_amdgcn_mfma_f32_16x16x32_f16(Al0, Bh, aL[0][cf], 0, 0, 0); \
      aL[1][cf] = __builtin_amdgcn_mfma_f32_16x16x32_f16(Ah1, Bl, aL[1][cf], 0, 0, 0); \
      aL[1][cf] = __builtin_amdgcn_mfma_f32_16x16x32_f16(Al1, Bh, aL[1][cf], 0, 0, 0); \
      aL[2][cf] = __builtin_amdgcn_mfma_f32_16x16x32_f16(Ah2, Bl, aL[2][cf], 0, 0, 0); \
      aL[2][cf] = __builtin_amdgcn_mfma_f32_16x16x32_f16(Al2, Bh, aL[2][cf], 0, 0, 0); \
      aL[3][cf] = __builtin_amdgcn_mfma_f32_16x16x32_f16(Ah3, Bl, aL[3][cf], 0, 0, 0); \
      aL[3][cf] = __builtin_amdgcn_mfma_f32_16x16x32_f16(Al3, Bh, aL[3][cf], 0, 0, 0); \
    }                                                                        \
  } while (0)

  STAGE_A_LOAD(0);
  STAGE_B(0, smem);
  STAGE_A_WRITE(smem);
  __syncthreads();                       // buf0 staged
  #pragma unroll 2
  for (int t = 0; t < 16; ++t) {
    char* cur = smem + (size_t)(t & 1) * SBUF;
    char* nxt = smem + (size_t)((t & 1) ^ 1) * SBUF;
    if (t < 15) { STAGE_A_LOAD(t + 1); STAGE_B(t + 1, nxt); }  // issue early
    COMPUTE(cur);                        // A-load + DMA latency hides here
    if (t < 15) STAGE_A_WRITE(nxt);      // write late (vmcnt waits A only)
    __syncthreads();                     // one barrier per K-step
  }
#undef STAGE_A_LOAD
#undef STAGE_B
#undef STAGE_A_WRITE
#undef COMPUTE

  float bj[5];
  #pragma unroll
  for (int cf = 0; cf < 5; ++cf) bj[cf] = bias[g * CN + wc * 80 + cf * 16 + l15];

  // two 64-row epilogue phases (lg = 83 KB aliases dead staging buffers)
  float pacc[5] = {0.f, 0.f, 0.f, 0.f, 0.f};
  #pragma unroll
  for (int p = 0; p < 2; ++p) {
    if (wr == p) {
      // C/D layout (HW-verified r4-r8): col = l15, row = l4*4 + e
      #pragma unroll
      for (int cf = 0; cf < 5; ++cf) {
        const int col = wc * 80 + cf * 16 + l15;
        #pragma unroll
        for (int rf = 0; rf < 4; ++rf)
          #pragma unroll
          for (int e = 0; e < 4; ++e)
            lg[(rf * 16 + l4 * 4 + e) * LSTR + col] =
                aH[rf][cf][e] + aL[rf][cf][e] * (1.f / 512.f) + bj[cf];
      }
    }
    __syncthreads();
    // all 8 waves: 8 rows each (verified row epilogue, r3-r8)
    #pragma unroll
    for (int i = 0; i < 8; ++i) {
      const int rl = w * 8 + i;
      const int n  = m0 + p * 64 + rl;
      const size_t grow = ((size_t)n * GN + g) * CN;
      float lv[5], gv[5];
      #pragma unroll
      for (int j = 0; j < 5; ++j) lv[j] = lg[rl * LSTR + tc + 64 * j];
      #pragma unroll
      for (int j = 0; j < 5; ++j) gv[j] = gnoise[grow + tc + 64 * j];

      float bv = -3.4e38f; int bi = 1 << 30;
      #pragma unroll
      for (int j = 0; j < 5; ++j) {
        float v = lv[j] + gv[j];
        if (v > bv) { bv = v; bi = tc + 64 * j; }
      }
      for (int off = 1; off < 64; off <<= 1) {
        float ov = __shfl_xor(bv, off);
        int   oi = __shfl_xor(bi, off);
        if (ov > bv || (ov == bv && oi < bi)) { bv = ov; bi = oi; }
      }

      float mx = lv[0];
      #pragma unroll
      for (int j = 1; j < 5; ++j) mx = fmaxf(mx, lv[j]);
      for (int off = 1; off < 64; off <<= 1) mx = fmaxf(mx, __shfl_xor(mx, off));
      float e[5], s = 0.f;
      #pragma unroll
      for (int j = 0; j < 5; ++j) { e[j] = __expf(lv[j] - mx); s += e[j]; }
      for (int off = 1; off < 64; off <<= 1) s += __shfl_xor(s, off);
      const float inv = 1.f / s;
      const float mlt = (mask[n] != 0) ? 1.f : 0.f;
      #pragma unroll
      for (int j = 0; j < 5; ++j) pacc[j] += mlt * e[j] * inv;

      const float2* cvr = (const float2*)(cv + ((size_t)(g * CN + bi)) * DN);
      float2* o2 = (float2*)(out + (size_t)n * (GN * DN) + g * DN);
      o2[tc] = cvr[tc];
    }
    __syncthreads();
  }

  #pragma unroll
  for (int j = 0; j < 5; ++j) psum[w * CN + tc + 64 * j] = pacc[j];
  __syncthreads();
  for (int c = tid; c < CN; c += NTHR) {
    float s = 0.f;
    #pragma unroll
    for (int q = 0; q < 8; ++q) s += psum[q * CN + c];
    atomicAdd(&pp[g * CN + c], s);
  }
}

// ---------------- fp32 fallback (round-3 verified, BMF=32) ----------------
__global__ __launch_bounds__(NTHRF) void k_main_fp32(
    const float* __restrict__ x, const int* __restrict__ mask,
    const float* __restrict__ gnoise, const float* __restrict__ W,
    const float* __restrict__ bias, const float* __restrict__ cv,
    float* __restrict__ out, float* __restrict__ pp)
{
  __shared__ __align__(16) char fsmem[47360];
  float* w_lds = (float*)fsmem;
  float* xs    = (float*)(fsmem + 42240);
  float* lgf   = (float*)fsmem;
  float* psum  = (float*)(fsmem + 42240);

  const int m0  = blockIdx.x * BMF;
  const int g   = blockIdx.y;
  const int tid = threadIdx.x;
  const int tc  = tid & 63;
  const int tr  = tid >> 6;
  const int r0  = tr * 8;

  float acc[8][5];
  #pragma unroll
  for (int i = 0; i < 8; ++i)
    #pragma unroll
    for (int j = 0; j < 5; ++j) acc[i][j] = 0.f;

  const float* Wg = W + (size_t)g * CN * HD;

  for (int k0 = 0; k0 < HD; k0 += 32) {
    __syncthreads();
    #pragma unroll
    for (int t = 0; t < 10; ++t) {
      int idx = tid + t * NTHRF;
      int c   = idx >> 3;
      int k4  = idx & 7;
      float4 wv4 = *(const float4*)(Wg + (size_t)c * HD + k0 + k4 * 4);
      float* dst = &w_lds[c * WSTR + k4 * 4];
      dst[0] = wv4.x; dst[1] = wv4.y; dst[2] = wv4.z; dst[3] = wv4.w;
    }
    {
      int r = tid >> 3, k4 = tid & 7;
      float4 xv = *(const float4*)(x + (size_t)(m0 + r) * HD + k0 + k4 * 4);
      float* dst = &xs[r * 32 + k4 * 4];
      dst[0] = xv.x; dst[1] = xv.y; dst[2] = xv.z; dst[3] = xv.w;
    }
    __syncthreads();
    #pragma unroll
    for (int kk = 0; kk < 32; kk += 4) {
      float xq[8][4];
      #pragma unroll
      for (int i = 0; i < 8; ++i) {
        float4 t4 = *(const float4*)&xs[(r0 + i) * 32 + kk];
        xq[i][0] = t4.x; xq[i][1] = t4.y; xq[i][2] = t4.z; xq[i][3] = t4.w;
      }
      #pragma unroll
      for (int q = 0; q < 4; ++q) {
        float wv[5];
        #pragma unroll
        for (int j = 0; j < 5; ++j) wv[j] = w_lds[(tc + 64 * j) * WSTR + kk + q];
        #pragma unroll
        for (int i = 0; i < 8; ++i)
          #pragma unroll
          for (int j = 0; j < 5; ++j)
            acc[i][j] = fmaf(xq[i][q], wv[j], acc[i][j]);
      }
    }
  }
  __syncthreads();

  float bj[5];
  #pragma unroll
  for (int j = 0; j < 5; ++j) bj[j] = bias[g * CN + tc + 64 * j];
  #pragma unroll
  for (int i = 0; i < 8; ++i)
    #pragma unroll
    for (int j = 0; j < 5; ++j)
      lgf[(r0 + i) * CN + tc + 64 * j] = acc[i][j] + bj[j];
  __syncthreads();

  float pacc[5] = {0.f, 0.f, 0.f, 0.f, 0.f};
  #pragma unroll
  for (int i = 0; i < 8; ++i) {
    const int r = r0 + i;
    const int n = m0 + r;
    const size_t grow = ((size_t)n * GN + g) * CN;
    float lv[5], gv[5];
    #pragma unroll
    for (int j = 0; j < 5; ++j) lv[j] = lgf[r * CN + tc + 64 * j];
    #pragma unroll
    for (int j = 0; j < 5; ++j) gv[j] = gnoise[grow + tc + 64 * j];

    float bv = -3.4e38f; int bi = 1 << 30;
    #pragma unroll
    for (int j = 0; j < 5; ++j) {
      float v = lv[j] + gv[j];
      if (v > bv) { bv = v; bi = tc + 64 * j; }
    }
    for (int off = 1; off < 64; off <<= 1) {
      float ov = __shfl_xor(bv, off);
      int   oi = __shfl_xor(bi, off);
      if (ov > bv || (ov == bv && oi < bi)) { bv = ov; bi = oi; }
    }

    float mx = lv[0];
    #pragma unroll
    for (int j = 1; j < 5; ++j) mx = fmaxf(mx, lv[j]);
    for (int off = 1; off < 64; off <<= 1) mx = fmaxf(mx, __shfl_xor(mx, off));
    float e[5], s = 0.f;
    #pragma unroll
    for (int j = 0; j < 5; ++j) { e[j] = expf(lv[j] - mx); s += e[j]; }
    for (int off = 1; off < 64; off <<= 1) s += __shfl_xor(s, off);
    const float inv = 1.f / s;
    const float mlt = (mask[n] != 0) ? 1.f : 0.f;
    #pragma unroll
    for (int j = 0; j < 5; ++j) pacc[j] += mlt * e[j] * inv;

    const float2* cvr = (const float2*)(cv + ((size_t)(g * CN + bi)) * DN);
    float2* o2 = (float2*)(out + (size_t)n * (GN * DN) + g * DN);
    o2[tc] = cvr[tc];
  }

  #pragma unroll
  for (int j = 0; j < 5; ++j) psum[tr * CN + tc + 64 * j] = pacc[j];
  __syncthreads();
  for (int c = tid; c < CN; c += NTHRF) {
    float s = psum[c] + psum[CN + c] + psum[2 * CN + c] + psum[3 * CN + c];
    atomicAdd(&pp[g * CN + c], s);
  }
}

// ---------------- perplexity finalize ----------------
__global__ __launch_bounds__(640) void k_final(
    const float* __restrict__ pp, const int* __restrict__ mask,
    float* __restrict__ out, int out_off)
{
  __shared__ float red[10];
  __shared__ float eL[GN * CN];
  __shared__ float perp_parts[GN];
  const int tid = threadIdx.x;

  float cnt = 0.f;
  for (int i = tid; i < TOKS; i += 640) cnt += (mask[i] != 0) ? 1.f : 0.f;
  for (int off = 1; off < 64; off <<= 1) cnt += __shfl_xor(cnt, off);
  if ((tid & 63) == 0) red[tid >> 6] = cnt;
  __syncthreads();
  float denom = 0.f;
  #pragma unroll
  for (int w = 0; w < 10; ++w) denom += red[w];
  denom = fmaxf(denom, 1.f);

  const float p = pp[tid] / denom;
  eL[tid] = p * logf(p + 1e-7f);
  __syncthreads();

  if (tid < 2 * 64) {
    const int gg = tid >> 6, ll = tid & 63;
    float s = 0.f;
    #pragma unroll
    for (int j = 0; j < 5; ++j) s += eL[gg * CN + ll + 64 * j];
    for (int off = 1; off < 64; off <<= 1) s += __shfl_xor(s, off);
    if (ll == 0) perp_parts[gg] = expf(-s);
  }
  __syncthreads();
  if (tid == 0) out[out_off] = perp_parts[0] + perp_parts[1];
}

extern "C" void kernel_launch(void* const* d_in, const int* in_sizes, int n_in,
                              void* d_out, int out_size, void* d_ws, size_t ws_size,
                              hipStream_t stream) {
  const float* x     = (const float*)d_in[0];
  const int*   mask  = (const int*)d_in[1];
  const float* gn    = (const float*)d_in[2];
  const float* W     = (const float*)d_in[3];
  const float* bias  = (const float*)d_in[4];
  const float* cv    = (const float*)d_in[5];
  float* out = (float*)d_out;
  float* pp  = (float*)d_ws;

  if (ws_size >= WS_MID) {
    _Float16* wh = (_Float16*)((char*)d_ws + WS_W_OFF);
    _Float16* wl = wh + WS_WELEMS;
    hipLaunchKernelGGL(k_split, dim3((int)(WS_WELEMS / 8 / 256)), dim3(256), 0,
                       stream, W, wh, wl, pp);
    hipLaunchKernelGGL(k_gemm_ep, dim3(TOKS / BM * GN), dim3(NTHR), SMEM_DYN,
                       stream, x, mask, gn, bias, cv, wh, wl, out, pp);
  } else {
    hipLaunchKernelGGL(k_zero, dim3(1), dim3(640), 0, stream, pp);
    hipLaunchKernelGGL(k_main_fp32, dim3(TOKS / BMF, GN), dim3(NTHRF), 0, stream,
                       x, mask, gn, W, bias, cv, out, pp);
  }

  hipLaunchKernelGGL(k_final, dim3(1), dim3(640), 0, stream,
                     pp, mask, out, out_size - 1);
}